// Round 1
// baseline (360.698 us; speedup 1.0000x reference)
//
#include <hip/hip_runtime.h>
#include <hip/hip_bf16.h>

#ifndef BN_EPS
#define BN_EPS 1e-5f
#endif

// ---------------------------------------------------------------------------
// N=100000, C=64, E=1600000.
// R12: L2-resident sliced aggregation.
//   k_agg was L2-miss-latency bound (166MB fetch = thrash of 12.8MB xb over
//   4MB/XCD L2 at ~600cy LLC latency). Fix: xb stored as 4 channel-slices of
//   3.2MB (< 4MB L2/XCD); k_agg runs pass-outer so every XCD's L2 holds the
//   active slice -> gathers become ~200cy L2 hits, fetch drops to cold-fill
//   replication floor (~102MB) + csr re-reads.
//   Rows pre-scaled by dinv[src] (xb2 = bf16(dinv*x)): removes per-edge dinv
//   gather + w-shuffles from the dependence chain. Requires deg before
//   conversion: deg via global atomics in k_pre; conversion fused into k_sub
//   dispatch; k_csr keeps offs only.
// Still 8 dispatches: memset, pre(bin+deg), scanSub, sub+conv, csr, agg,
// gemm1, gemm2. bias cancels inside BatchNorm, skipped.
// ---------------------------------------------------------------------------

#define NPB 8192
#define NPB_SHIFT 13

__device__ __forceinline__ unsigned short f2bf(float f) {
    unsigned u = __float_as_uint(f);
    u += 0x7FFF + ((u >> 16) & 1);  // round-to-nearest-even
    return (unsigned short)(u >> 16);
}
__device__ __forceinline__ float bf2f(unsigned v) {
    return __uint_as_float(v << 16);
}

// Coarse 13-bucket LDS chunk-sort (slack-capacity regions, cursor in bcnt) +
// 832-subbucket histogram (cnt2) + per-node in-degree (deg, global atomics).
__global__ __launch_bounds__(256) void k_pre(const int* __restrict__ src,
                                             const int* __restrict__ dst,
                                             int* __restrict__ deg,
                                             int* __restrict__ cnt2,
                                             int* __restrict__ bcnt,
                                             unsigned* __restrict__ binned,
                                             int E, int SUBTOT, int cap) {
    __shared__ int hist[16], hexcl[16], hcur[16], gbase[16];
    __shared__ int h2[1024];
    __shared__ unsigned lout[4096];
    __shared__ unsigned char lb[4096];
    int tid = threadIdx.x;
    int c0 = blockIdx.x * 4096;
    if (c0 >= E) return;
    int cnt = min(4096, E - c0);
    if (tid < 16) hist[tid] = 0;
    for (int i = tid; i < SUBTOT; i += 256) h2[i] = 0;
    __syncthreads();
    for (int i = tid; i < cnt; i += 256) {
        int d = dst[c0 + i];
        atomicAdd(&hist[d >> NPB_SHIFT], 1);
        atomicAdd(&h2[d >> 7], 1);
        atomicAdd(&deg[d], 1);
    }
    __syncthreads();
    if (tid == 0) {
        int acc = 0;
        for (int b = 0; b < 16; b++) { hexcl[b] = acc; hcur[b] = acc; acc += hist[b]; }
    }
    __syncthreads();
    if (tid < 16 && hist[tid] > 0) gbase[tid] = atomicAdd(&bcnt[tid], hist[tid]);
    for (int i = tid; i < SUBTOT; i += 256) {
        int v = h2[i];
        if (v > 0) atomicAdd(&cnt2[i], v);
    }
    for (int i = tid; i < cnt; i += 256) {
        int d = dst[c0 + i];
        int s = src[c0 + i];
        int b = d >> NPB_SHIFT;
        unsigned packed = (unsigned)s | ((unsigned)(d & (NPB - 1)) << 17);
        int p = atomicAdd(&hcur[b], 1);
        lout[p] = packed;
        lb[p] = (unsigned char)b;
    }
    __syncthreads();
    for (int i = tid; i < cnt; i += 256) {
        int b = lb[i];
        binned[(size_t)b * cap + gbase[b] + (i - hexcl[b])] = lout[i];
    }
}

// Exact scan of cnt2 -> sbase (excl, +sentinel), scur copy; also zeroes stats.
__global__ __launch_bounds__(1024) void k_scanSub(const int* __restrict__ cnt2,
                                                  int* __restrict__ sbase,
                                                  int* __restrict__ scur,
                                                  float* __restrict__ stats,
                                                  int SUBTOT, int E) {
    __shared__ int s[1024];
    int t = threadIdx.x;
    if (t < 128) stats[t] = 0.f;
    int v = (t < SUBTOT) ? cnt2[t] : 0;
    s[t] = v;
    __syncthreads();
    for (int off = 1; off < 1024; off <<= 1) {
        int add = (t >= off) ? s[t - off] : 0;
        __syncthreads();
        s[t] += add;
        __syncthreads();
    }
    if (t < SUBTOT) {
        int excl = s[t] - v;
        sbase[t] = excl;
        scur[t] = excl;
    }
    if (t == 0) sbase[SUBTOT] = E;
}

// Blocks [0, B*32): per coarse bucket chunk-sort into 64 sub-buckets at exact
// scur offsets. Blocks [B*32, ...): x -> xb2 conversion, pre-scaled by
// dinv[n]=rsqrt(deg+1), written as 4 channel-slices of N*32B each
// (slice t holds channels 16t..16t+15); also stores dinv[].
__global__ __launch_bounds__(256) void k_sub(const unsigned* __restrict__ binned,
                                             const int* __restrict__ sbase,
                                             int* __restrict__ scur,
                                             unsigned* __restrict__ sorted2,
                                             const float* __restrict__ x,
                                             const int* __restrict__ deg,
                                             unsigned* __restrict__ xs,
                                             float* __restrict__ dinv,
                                             int cap, int B, int N) {
    __shared__ int hist[64], hexcl[64], hcur[64], gbase[64];
    __shared__ unsigned lout[4096];
    __shared__ unsigned char lb[4096];
    int bid = blockIdx.x;
    if (bid >= B * 32) {  // conversion path (block-uniform)
        int i = (bid - B * 32) * 256 + threadIdx.x;  // over N*16 float4s
        if (i < N * 16) {
            int n = i >> 4;
            int c4 = i & 15;
            float dn = rsqrtf((float)(deg[n] + 1));  // +1 = self-loop
            float4 v = ((const float4*)x)[i];
            unsigned lo = (unsigned)f2bf(v.x * dn) | ((unsigned)f2bf(v.y * dn) << 16);
            unsigned hi = (unsigned)f2bf(v.z * dn) | ((unsigned)f2bf(v.w * dn) << 16);
            int t = c4 >> 2;
            uint2 w2 = {lo, hi};
            *(uint2*)(xs + (size_t)t * N * 8 + n * 8 + (c4 & 3) * 2) = w2;
            if (c4 == 0) dinv[n] = dn;
        }
        return;
    }
    int b = bid >> 5;
    int r = bid & 31;
    if (b >= B) return;
    int tid = threadIdx.x;
    int total = sbase[(b + 1) << 6] - sbase[b << 6];
    const unsigned* bb = binned + (size_t)b * cap;
    for (int c0 = r * 4096; c0 < total; c0 += 32 * 4096) {
        int cnt = min(4096, total - c0);
        if (tid < 64) hist[tid] = 0;
        __syncthreads();
        for (int i = tid; i < cnt; i += 256)
            atomicAdd(&hist[(bb[c0 + i] >> 24) & 63], 1);  // local13>>7
        __syncthreads();
        if (tid == 0) {
            int acc = 0;
            for (int f = 0; f < 64; f++) { hexcl[f] = acc; hcur[f] = acc; acc += hist[f]; }
        }
        __syncthreads();
        if (tid < 64 && hist[tid] > 0)
            gbase[tid] = atomicAdd(&scur[(b << 6) + tid], hist[tid]);
        for (int i = tid; i < cnt; i += 256) {
            unsigned e = bb[c0 + i];
            int f = (e >> 24) & 63;
            unsigned rp = (e & 0x1FFFFu) | (((e >> 17) & 127u) << 17);
            int p = atomicAdd(&hcur[f], 1);
            lout[p] = rp;
            lb[p] = (unsigned char)f;
        }
        __syncthreads();
        for (int i = tid; i < cnt; i += 256) {
            int f = lb[i];
            sorted2[gbase[f] + (i - hexcl[f])] = lout[i];
        }
        __syncthreads();
    }
}

// One block per 128-node sub-bucket: private csr window scatter + offs from
// the LDS histogram. deg/dinv already exist (k_pre atomics / conversion).
__global__ __launch_bounds__(256) void k_csr(const unsigned* __restrict__ sorted2,
                                             const int* __restrict__ sbase,
                                             int* __restrict__ offs,
                                             int* __restrict__ csr, int N) {
    __shared__ int hist[128], lbase[128], lcur[128];
    int s = blockIdx.x;
    int j0 = sbase[s], j1 = sbase[s + 1];
    int tid = threadIdx.x;
    if (tid < 128) { hist[tid] = 0; lcur[tid] = 0; }
    __syncthreads();
    for (int j = j0 + tid; j < j1; j += 256)
        atomicAdd(&hist[sorted2[j] >> 17], 1);
    __syncthreads();
    if (tid == 0) {
        int acc = 0;
        for (int k = 0; k < 128; k++) { lbase[k] = acc; acc += hist[k]; }
    }
    __syncthreads();
    if (tid < 128) {
        int n = (s << 7) + tid;
        if (n < N) offs[n] = j0 + lbase[tid];  // csr is globally dst-ordered
    }
    for (int j = j0 + tid; j < j1; j += 256) {
        unsigned e = sorted2[j];
        int ld = e >> 17;
        int pos = j0 + lbase[ld] + atomicAdd(&lcur[ld], 1);
        csr[pos] = (int)(e & 0x1FFFFu);
    }
}

// Wave per node, 4 channel-slice passes (pass-outer so each XCD's L2 holds
// the active 3.2MB slice -> gathers are L2 hits). lane = (edge h=lane>>3,
// channel-pair p=lane&7): one 4B load = 2 channels of one of 8 edges.
// Rows pre-scaled by dinv[src] -> plain adds, no weight shuffle/gather.
__global__ __launch_bounds__(256) void k_agg(const int* __restrict__ offs,
                                             const int* __restrict__ deg,
                                             const int* __restrict__ csr,
                                             const unsigned* __restrict__ xs,
                                             const float* __restrict__ dinv,
                                             unsigned* __restrict__ aggb32, int N) {
    int lane = threadIdx.x & 63;
    int p = lane & 7;   // channel pair within slice
    int h = lane >> 3;  // which edge of a group of 8
    int wid = (blockIdx.x * 256 + threadIdx.x) >> 6;
    int nw = (gridDim.x * 256) >> 6;

    for (int t = 0; t < 4; ++t) {
        const unsigned* xt = xs + (size_t)t * N * 8;
        for (int n = wid; n < N; n += nw) {
            float dn = dinv[n];
            unsigned sv = xt[n * 8 + p];  // self-loop term (pre-scaled)
            float accx = (h == 0) ? bf2f(sv & 0xFFFFu) : 0.f;
            float accy = (h == 0) ? bf2f(sv >> 16) : 0.f;
            int j0 = offs[n];
            int j1 = j0 + deg[n];
            for (int jb = j0; jb < j1; jb += 64) {
                int cnt = min(64, j1 - jb);
                int idx = 0;
                if (lane < cnt) idx = csr[jb + lane];
                int j = 0;
                for (; j + 32 <= cnt; j += 32) {
                    int s0 = __shfl(idx, j + h);
                    int s1 = __shfl(idx, j + 8 + h);
                    int s2 = __shfl(idx, j + 16 + h);
                    int s3 = __shfl(idx, j + 24 + h);
                    unsigned v0 = xt[s0 * 8 + p];
                    unsigned v1 = xt[s1 * 8 + p];
                    unsigned v2 = xt[s2 * 8 + p];
                    unsigned v3 = xt[s3 * 8 + p];
                    accx += bf2f(v0 & 0xFFFFu); accy += bf2f(v0 >> 16);
                    accx += bf2f(v1 & 0xFFFFu); accy += bf2f(v1 >> 16);
                    accx += bf2f(v2 & 0xFFFFu); accy += bf2f(v2 >> 16);
                    accx += bf2f(v3 & 0xFFFFu); accy += bf2f(v3 >> 16);
                }
                for (; j + 16 <= cnt; j += 16) {
                    int s0 = __shfl(idx, j + h);
                    int s1 = __shfl(idx, j + 8 + h);
                    unsigned v0 = xt[s0 * 8 + p];
                    unsigned v1 = xt[s1 * 8 + p];
                    accx += bf2f(v0 & 0xFFFFu); accy += bf2f(v0 >> 16);
                    accx += bf2f(v1 & 0xFFFFu); accy += bf2f(v1 >> 16);
                }
                for (; j + 8 <= cnt; j += 8) {
                    int s0 = __shfl(idx, j + h);
                    unsigned v0 = xt[s0 * 8 + p];
                    accx += bf2f(v0 & 0xFFFFu); accy += bf2f(v0 >> 16);
                }
                int rem = cnt - j;
                if (rem > 0) {  // <8 tail: lanes h<rem contribute
                    int s0 = __shfl(idx, j + (h < rem ? h : 0));
                    unsigned v0 = xt[s0 * 8 + p];
                    if (h < rem) { accx += bf2f(v0 & 0xFFFFu); accy += bf2f(v0 >> 16); }
                }
            }
            accx += __shfl_xor(accx, 8);  accy += __shfl_xor(accy, 8);
            accx += __shfl_xor(accx, 16); accy += __shfl_xor(accy, 16);
            accx += __shfl_xor(accx, 32); accy += __shfl_xor(accy, 32);
            if (h == 0) {
                unsigned o = (unsigned)f2bf(accx * dn) | ((unsigned)f2bf(accy * dn) << 16);
                aggb32[(size_t)n * 32 + t * 8 + p] = o;
            }
        }
    }
}

// Stats pass: o = agg@W per row (same structure as k_gemm2, NO stores).
__global__ __launch_bounds__(256) void k_gemm1(const unsigned* __restrict__ aggb32,
                                               const float* __restrict__ W,
                                               float* __restrict__ stats, int N) {
    __shared__ unsigned tile[256 * 32];
    __shared__ float red[512];  // [2][4][64]
    int t = threadIdx.x;
    int lane = t & 63;
    int w = t >> 6;
    int r0 = blockIdx.x * 256;
    const uint4* gp = (const uint4*)(aggb32 + (size_t)r0 * 32);
#pragma unroll
    for (int i = 0; i < 8; i++) {
        int idx = t + 256 * i;
        int n = r0 + (idx >> 3);
        uint4 v = {0u, 0u, 0u, 0u};
        if (n < N) v = gp[idx];
        *(uint4*)(tile + idx * 4) = v;
    }
    float wcol[64];
#pragma unroll
    for (int k = 0; k < 64; k++) wcol[k] = W[k * 64 + lane];
    __syncthreads();

    float psum = 0.f, psq = 0.f;
    for (int rr = 0; rr < 64; rr += 2) {
        int lr0 = w * 64 + rr;
        int n0 = r0 + lr0;
        if (n0 >= N) break;
        const unsigned* row0 = tile + lr0 * 32;
        const unsigned* row1 = row0 + 32;
        float o0 = 0.f, o1 = 0.f;
#pragma unroll
        for (int kp = 0; kp < 32; kp++) {
            unsigned u0 = row0[kp], u1 = row1[kp];
            o0 = fmaf(bf2f(u0 & 0xFFFFu), wcol[2 * kp], o0);
            o0 = fmaf(bf2f(u0 >> 16), wcol[2 * kp + 1], o0);
            o1 = fmaf(bf2f(u1 & 0xFFFFu), wcol[2 * kp], o1);
            o1 = fmaf(bf2f(u1 >> 16), wcol[2 * kp + 1], o1);
        }
        psum += o0;
        psq = fmaf(o0, o0, psq);
        if (n0 + 1 < N) {
            psum += o1;
            psq = fmaf(o1, o1, psq);
        }
    }
    red[w * 64 + lane] = psum;
    red[256 + w * 64 + lane] = psq;
    __syncthreads();
    if (w == 0) {
        float s = red[lane] + red[64 + lane] + red[128 + lane] + red[192 + lane];
        atomicAdd(&stats[lane], s);
    } else if (w == 1) {
        float q = red[256 + lane] + red[320 + lane] + red[384 + lane] + red[448 + lane];
        atomicAdd(&stats[64 + lane], q);
    }
}

// out = BN(agg@W)+ReLU, BN scale/shift derived in-prologue from stats.
__global__ __launch_bounds__(256) void k_gemm2(const unsigned* __restrict__ aggb32,
                                               const float* __restrict__ W,
                                               const float* __restrict__ stats,
                                               const float* __restrict__ gamma,
                                               const float* __restrict__ beta,
                                               float* __restrict__ out, int N,
                                               float invN) {
    __shared__ unsigned tile[256 * 32];
    __shared__ float ssl[128];
    int t = threadIdx.x;
    int lane = t & 63;
    int w = t >> 6;
    int r0 = blockIdx.x * 256;
    const uint4* gp = (const uint4*)(aggb32 + (size_t)r0 * 32);
#pragma unroll
    for (int i = 0; i < 8; i++) {
        int idx = t + 256 * i;
        int n = r0 + (idx >> 3);
        uint4 v = {0u, 0u, 0u, 0u};
        if (n < N) v = gp[idx];
        *(uint4*)(tile + idx * 4) = v;
    }
    if (t < 64) {  // bnprep folded in (redundant per block, trivial)
        float mean = stats[t] * invN;
        float var = stats[64 + t] * invN - mean * mean;  // biased var
        float sc = gamma[t] * rsqrtf(var + BN_EPS);
        ssl[t] = sc;
        ssl[64 + t] = beta[t] - mean * sc;
    }
    float wcol[64];
#pragma unroll
    for (int k = 0; k < 64; k++) wcol[k] = W[k * 64 + lane];
    __syncthreads();
    float sc = ssl[lane], sh = ssl[64 + lane];

    for (int rr = 0; rr < 64; rr += 2) {
        int lr0 = w * 64 + rr;
        int n0 = r0 + lr0;
        if (n0 >= N) break;
        const unsigned* row0 = tile + lr0 * 32;
        const unsigned* row1 = row0 + 32;
        float o0 = 0.f, o1 = 0.f;
#pragma unroll
        for (int kp = 0; kp < 32; kp++) {
            unsigned u0 = row0[kp], u1 = row1[kp];
            o0 = fmaf(bf2f(u0 & 0xFFFFu), wcol[2 * kp], o0);
            o0 = fmaf(bf2f(u0 >> 16), wcol[2 * kp + 1], o0);
            o1 = fmaf(bf2f(u1 & 0xFFFFu), wcol[2 * kp], o1);
            o1 = fmaf(bf2f(u1 >> 16), wcol[2 * kp + 1], o1);
        }
        o0 = fmaxf(fmaf(o0, sc, sh), 0.f);
        o1 = fmaxf(fmaf(o1, sc, sh), 0.f);
        out[(size_t)n0 * 64 + lane] = o0;
        if (n0 + 1 < N) out[(size_t)(n0 + 1) * 64 + lane] = o1;
    }
}

extern "C" void kernel_launch(void* const* d_in, const int* in_sizes, int n_in,
                              void* d_out, int out_size, void* d_ws, size_t ws_size,
                              hipStream_t stream) {
    const float* x = (const float*)d_in[0];
    const int* ei = (const int*)d_in[1];
    const float* W = (const float*)d_in[2];
    // d_in[3] = bias: cancels inside BatchNorm, unused.
    const float* gamma = (const float*)d_in[4];
    const float* beta = (const float*)d_in[5];
    float* out = (float*)d_out;

    const int N = in_sizes[0] / 64;
    const int E = in_sizes[1] / 2;
    const int* src = ei;
    const int* dst = ei + E;
    const int NB = (N + 255) / 256;             // 391
    const int B = (N + NPB - 1) >> NPB_SHIFT;   // 13 coarse buckets
    const int SUBTOT = B * 64;                  // 832 sub-buckets (<=1024)
    // Slack capacity per coarse bucket: mean ~131K, sigma ~350; +16384 = +53
    // sigma -> overflow impossible.
    const int cap = E / 12 + 16384;

    char* ws = (char*)d_ws;
    size_t o = 0;
    float* stats = (float*)(ws + o); o += 512;       // zeroed in k_scanSub
    int* cnt2 = (int*)(ws + o); o += 4096;           // 832 ints used
    int* bcnt = (int*)(ws + o); o += 64;             // 13 coarse cursors
    int* deg = (int*)(ws + o); o += (size_t)4 * N;   // atomic in-degree
    size_t z0 = 512, z1 = 4096 + 64 + (size_t)4 * N; // memset cnt2+bcnt+deg
    int* sbase = (int*)(ws + o); o += 3584;          // SUBTOT+1 ints
    int* scur = (int*)(ws + o); o += 3584;
    int* offs = (int*)(ws + o); o += (size_t)4 * N;
    float* dinv = (float*)(ws + o); o += (size_t)4 * N;
    unsigned* xs = (unsigned*)(ws + o); o += (size_t)128 * N;   // 4 slices
    unsigned* aggb32 = (unsigned*)(ws + o); o += (size_t)128 * N;
    unsigned* binned = (unsigned*)(ws + o); o += (size_t)4 * B * cap;
    unsigned* sorted2 = (unsigned*)(ws + o); o += (size_t)4 * E;
    int* csr = (int*)binned;  // alias: binned consumed by k_sub before k_csr

    hipMemsetAsync(ws + z0, 0, z1, stream);

    const int EB = (E + 4095) / 4096;            // 391 binning blocks
    const int CB = (N * 16 + 255) / 256;         // 6250 conversion blocks
    k_pre<<<EB, 256, 0, stream>>>(src, dst, deg, cnt2, bcnt, binned,
                                  E, SUBTOT, cap);
    k_scanSub<<<1, 1024, 0, stream>>>(cnt2, sbase, scur, stats, SUBTOT, E);
    k_sub<<<B * 32 + CB, 256, 0, stream>>>(binned, sbase, scur, sorted2,
                                           x, deg, xs, dinv, cap, B, N);
    k_csr<<<SUBTOT, 256, 0, stream>>>(sorted2, sbase, offs, csr, N);
    k_agg<<<2048, 256, 0, stream>>>(offs, deg, csr, xs, dinv, aggb32, N);
    k_gemm1<<<NB, 256, 0, stream>>>(aggb32, W, stats, N);
    k_gemm2<<<NB, 256, 0, stream>>>(aggb32, W, stats, gamma, beta, out, N,
                                    1.0f / (float)N);
}

// Round 2
// 251.680 us; speedup vs baseline: 1.4332x; 1.4332x over previous
//
#include <hip/hip_runtime.h>
#include <hip/hip_bf16.h>

#ifndef BN_EPS
#define BN_EPS 1e-5f
#endif

// ---------------------------------------------------------------------------
// N=100000, C=64, E=1600000.
// R13: revert to R11 (proven 253.6us) + k_agg 16-edge/8-load pipelining.
//   R12 post-mortem: 4-pass slicing cut FETCH 166->130MB but doubled k_agg
//   (per-node overhead x4 at avg deg=16; VALU-instrs 6.5M->17M). Bytes are
//   not the binding constraint -- per-wave load concurrency is.
//   R13 k_agg: per 64-edge window, process 16 edges per group: 16 shfls ->
//   8 independent gathers issued back-to-back -> 16 FMAs. Lanes >= cnt hold
//   (idx=0,w=0) so overshoot slots are w=0 * row0 (L1-hot) -- no serialized
//   2/1-edge tails (~half of nodes have deg<16).
// 8 dispatches: memset, pre(bin+conv), scanSub, sub, csr, agg, gemm1, gemm2.
// bias cancels inside BatchNorm, skipped.
// ---------------------------------------------------------------------------

#define NPB 8192
#define NPB_SHIFT 13

__device__ __forceinline__ unsigned short f2bf(float f) {
    unsigned u = __float_as_uint(f);
    u += 0x7FFF + ((u >> 16) & 1);  // round-to-nearest-even
    return (unsigned short)(u >> 16);
}
__device__ __forceinline__ float bf2f(unsigned v) {
    return __uint_as_float(v << 16);
}

// Fused: coarse 13-bucket LDS chunk-sort (slack-capacity regions, cursor in
// bcnt) + 832-subbucket histogram (cnt2) + x->bf16.
__global__ __launch_bounds__(256) void k_pre(const float* __restrict__ x,
                                             const int* __restrict__ src,
                                             const int* __restrict__ dst,
                                             unsigned short* __restrict__ xb,
                                             int* __restrict__ cnt2,
                                             int* __restrict__ bcnt,
                                             unsigned* __restrict__ binned,
                                             int E, int n4, int SUBTOT, int cap) {
    __shared__ int hist[16], hexcl[16], hcur[16], gbase[16];
    __shared__ int h2[1024];
    __shared__ unsigned lout[4096];
    __shared__ unsigned char lb[4096];
    int tid = threadIdx.x;
    int c0 = blockIdx.x * 4096;
    if (c0 < E) {  // block-uniform branch
        int cnt = min(4096, E - c0);
        if (tid < 16) hist[tid] = 0;
        for (int i = tid; i < SUBTOT; i += 256) h2[i] = 0;
        __syncthreads();
        for (int i = tid; i < cnt; i += 256) {
            int d = dst[c0 + i];
            atomicAdd(&hist[d >> NPB_SHIFT], 1);
            atomicAdd(&h2[d >> 7], 1);
        }
        __syncthreads();
        if (tid == 0) {
            int acc = 0;
            for (int b = 0; b < 16; b++) { hexcl[b] = acc; hcur[b] = acc; acc += hist[b]; }
        }
        __syncthreads();
        if (tid < 16 && hist[tid] > 0) gbase[tid] = atomicAdd(&bcnt[tid], hist[tid]);
        for (int i = tid; i < SUBTOT; i += 256) {
            int v = h2[i];
            if (v > 0) atomicAdd(&cnt2[i], v);
        }
        for (int i = tid; i < cnt; i += 256) {
            int d = dst[c0 + i];
            int s = src[c0 + i];
            int b = d >> NPB_SHIFT;
            unsigned packed = (unsigned)s | ((unsigned)(d & (NPB - 1)) << 17);
            int p = atomicAdd(&hcur[b], 1);
            lout[p] = packed;
            lb[p] = (unsigned char)b;
        }
        __syncthreads();
        for (int i = tid; i < cnt; i += 256) {
            int b = lb[i];
            binned[(size_t)b * cap + gbase[b] + (i - hexcl[b])] = lout[i];
        }
    }
    int i = blockIdx.x * 256 + tid;
    if (i < n4) {
        float4 v = ((const float4*)x)[i];
        ushort4 b;
        b.x = f2bf(v.x); b.y = f2bf(v.y); b.z = f2bf(v.z); b.w = f2bf(v.w);
        ((ushort4*)xb)[i] = b;
    }
}

// Exact scan of cnt2 -> sbase (excl, +sentinel), scur copy; also zeroes stats.
__global__ __launch_bounds__(1024) void k_scanSub(const int* __restrict__ cnt2,
                                                  int* __restrict__ sbase,
                                                  int* __restrict__ scur,
                                                  float* __restrict__ stats,
                                                  int SUBTOT, int E) {
    __shared__ int s[1024];
    int t = threadIdx.x;
    if (t < 128) stats[t] = 0.f;
    int v = (t < SUBTOT) ? cnt2[t] : 0;
    s[t] = v;
    __syncthreads();
    for (int off = 1; off < 1024; off <<= 1) {
        int add = (t >= off) ? s[t - off] : 0;
        __syncthreads();
        s[t] += add;
        __syncthreads();
    }
    if (t < SUBTOT) {
        int excl = s[t] - v;
        sbase[t] = excl;
        scur[t] = excl;
    }
    if (t == 0) sbase[SUBTOT] = E;
}

// Per coarse bucket (32 blocks each): chunk-sort into 64 sub-buckets at exact
// scur offsets. in: binned region [b*cap, b*cap+total). out: src | local7<<17.
__global__ __launch_bounds__(256) void k_sub(const unsigned* __restrict__ binned,
                                             const int* __restrict__ sbase,
                                             int* __restrict__ scur,
                                             unsigned* __restrict__ sorted2,
                                             int cap, int B) {
    __shared__ int hist[64], hexcl[64], hcur[64], gbase[64];
    __shared__ unsigned lout[4096];
    __shared__ unsigned char lb[4096];
    int b = blockIdx.x >> 5;
    int r = blockIdx.x & 31;
    if (b >= B) return;
    int tid = threadIdx.x;
    int total = sbase[(b + 1) << 6] - sbase[b << 6];
    const unsigned* bb = binned + (size_t)b * cap;
    for (int c0 = r * 4096; c0 < total; c0 += 32 * 4096) {
        int cnt = min(4096, total - c0);
        if (tid < 64) hist[tid] = 0;
        __syncthreads();
        for (int i = tid; i < cnt; i += 256)
            atomicAdd(&hist[(bb[c0 + i] >> 24) & 63], 1);  // local13>>7
        __syncthreads();
        if (tid == 0) {
            int acc = 0;
            for (int f = 0; f < 64; f++) { hexcl[f] = acc; hcur[f] = acc; acc += hist[f]; }
        }
        __syncthreads();
        if (tid < 64 && hist[tid] > 0)
            gbase[tid] = atomicAdd(&scur[(b << 6) + tid], hist[tid]);
        for (int i = tid; i < cnt; i += 256) {
            unsigned e = bb[c0 + i];
            int f = (e >> 24) & 63;
            unsigned rp = (e & 0x1FFFFu) | (((e >> 17) & 127u) << 17);
            int p = atomicAdd(&hcur[f], 1);
            lout[p] = rp;
            lb[p] = (unsigned char)f;
        }
        __syncthreads();
        for (int i = tid; i < cnt; i += 256) {
            int f = lb[i];
            sorted2[gbase[f] + (i - hexcl[f])] = lout[i];
        }
        __syncthreads();
    }
}

// One block per 128-node sub-bucket: private csr window scatter (single CU ->
// L2 merges) + deg/dinv/offs from the LDS histogram (coalesced 512B stores).
__global__ __launch_bounds__(256) void k_csr(const unsigned* __restrict__ sorted2,
                                             const int* __restrict__ sbase,
                                             int* __restrict__ deg,
                                             float* __restrict__ dinv,
                                             int* __restrict__ offs,
                                             int* __restrict__ csr, int N) {
    __shared__ int hist[128], lbase[128], lcur[128];
    int s = blockIdx.x;
    int j0 = sbase[s], j1 = sbase[s + 1];
    int tid = threadIdx.x;
    if (tid < 128) { hist[tid] = 0; lcur[tid] = 0; }
    __syncthreads();
    for (int j = j0 + tid; j < j1; j += 256)
        atomicAdd(&hist[sorted2[j] >> 17], 1);
    __syncthreads();
    if (tid == 0) {
        int acc = 0;
        for (int k = 0; k < 128; k++) { lbase[k] = acc; acc += hist[k]; }
    }
    __syncthreads();
    if (tid < 128) {  // deg / dinv / offs for this sub-bucket's 128 nodes
        int n = (s << 7) + tid;
        if (n < N) {
            int d = hist[tid];
            deg[n] = d;
            dinv[n] = rsqrtf((float)(d + 1));  // +1 = self-loop
            offs[n] = j0 + lbase[tid];         // csr is globally dst-ordered
        }
    }
    for (int j = j0 + tid; j < j1; j += 256) {
        unsigned e = sorted2[j];
        int ld = e >> 17;
        int pos = j0 + lbase[ld] + atomicAdd(&lcur[ld], 1);
        csr[pos] = (int)(e & 0x1FFFFu);
    }
}

// Wave per node. lane = (half h, channel-pair p): one 4B load = 2 channels of
// one of 2 edges. 16-edge groups: 8 independent gathers in flight before any
// consumption. Lanes >= cnt hold (idx=0,w=0), so overshoot slots in a group
// read row 0 (single L1-hot line) with weight 0 -- no serialized tails.
__global__ __launch_bounds__(256) void k_agg(const int* __restrict__ offs,
                                             const int* __restrict__ deg,
                                             const int* __restrict__ csr,
                                             const unsigned short* __restrict__ xb,
                                             const float* __restrict__ dinv,
                                             unsigned* __restrict__ aggb32, int N) {
    int lane = threadIdx.x & 63;
    int p = lane & 31;   // channel pair (channels 2p, 2p+1)
    int h = lane >> 5;   // half: which edge of a pair this lane gathers
    int wid = (blockIdx.x * 256 + threadIdx.x) >> 6;
    int nw = (gridDim.x * 256) >> 6;
    const unsigned* xw = (const unsigned*)xb;

    for (int n = wid; n < N; n += nw) {
        float dn = dinv[n];
        unsigned sv = xw[(size_t)n * 32 + p];
        float wself = (h == 0) ? dn : 0.f;  // self-loop counted once
        float accx = bf2f(sv & 0xFFFFu) * wself;
        float accy = bf2f(sv >> 16) * wself;
        int j0 = offs[n];
        int j1 = j0 + deg[n];
        for (int jb = j0; jb < j1; jb += 64) {
            int cnt = min(64, j1 - jb);
            int idx = 0;
            float w = 0.f;
            if (lane < cnt) {
                idx = csr[jb + lane];
                w = dinv[idx];
            }
            for (int j = 0; j < cnt; j += 16) {
                int s0 = __shfl(idx, j + 0 + h),  s1 = __shfl(idx, j + 2 + h);
                int s2 = __shfl(idx, j + 4 + h),  s3 = __shfl(idx, j + 6 + h);
                int s4 = __shfl(idx, j + 8 + h),  s5 = __shfl(idx, j + 10 + h);
                int s6 = __shfl(idx, j + 12 + h), s7 = __shfl(idx, j + 14 + h);
                float w0 = __shfl(w, j + 0 + h),  w1 = __shfl(w, j + 2 + h);
                float w2 = __shfl(w, j + 4 + h),  w3 = __shfl(w, j + 6 + h);
                float w4 = __shfl(w, j + 8 + h),  w5 = __shfl(w, j + 10 + h);
                float w6 = __shfl(w, j + 12 + h), w7 = __shfl(w, j + 14 + h);
                unsigned v0 = xw[(size_t)s0 * 32 + p];
                unsigned v1 = xw[(size_t)s1 * 32 + p];
                unsigned v2 = xw[(size_t)s2 * 32 + p];
                unsigned v3 = xw[(size_t)s3 * 32 + p];
                unsigned v4 = xw[(size_t)s4 * 32 + p];
                unsigned v5 = xw[(size_t)s5 * 32 + p];
                unsigned v6 = xw[(size_t)s6 * 32 + p];
                unsigned v7 = xw[(size_t)s7 * 32 + p];
                accx = fmaf(w0, bf2f(v0 & 0xFFFFu), accx);
                accy = fmaf(w0, bf2f(v0 >> 16), accy);
                accx = fmaf(w1, bf2f(v1 & 0xFFFFu), accx);
                accy = fmaf(w1, bf2f(v1 >> 16), accy);
                accx = fmaf(w2, bf2f(v2 & 0xFFFFu), accx);
                accy = fmaf(w2, bf2f(v2 >> 16), accy);
                accx = fmaf(w3, bf2f(v3 & 0xFFFFu), accx);
                accy = fmaf(w3, bf2f(v3 >> 16), accy);
                accx = fmaf(w4, bf2f(v4 & 0xFFFFu), accx);
                accy = fmaf(w4, bf2f(v4 >> 16), accy);
                accx = fmaf(w5, bf2f(v5 & 0xFFFFu), accx);
                accy = fmaf(w5, bf2f(v5 >> 16), accy);
                accx = fmaf(w6, bf2f(v6 & 0xFFFFu), accx);
                accy = fmaf(w6, bf2f(v6 >> 16), accy);
                accx = fmaf(w7, bf2f(v7 & 0xFFFFu), accx);
                accy = fmaf(w7, bf2f(v7 >> 16), accy);
            }
        }
        accx += __shfl_xor(accx, 32);
        accy += __shfl_xor(accy, 32);
        if (h == 0) {
            unsigned o = (unsigned)f2bf(accx * dn) | ((unsigned)f2bf(accy * dn) << 16);
            aggb32[(size_t)n * 32 + p] = o;
        }
    }
}

// Stats pass: o = agg@W per row (same structure as k_gemm2, NO stores).
// lane=channel -> psum/psq in registers; LDS-reduce across 4 waves; 128
// atomics per block total.
__global__ __launch_bounds__(256) void k_gemm1(const unsigned* __restrict__ aggb32,
                                               const float* __restrict__ W,
                                               float* __restrict__ stats, int N) {
    __shared__ unsigned tile[256 * 32];
    __shared__ float red[512];  // [2][4][64]
    int t = threadIdx.x;
    int lane = t & 63;
    int w = t >> 6;
    int r0 = blockIdx.x * 256;
    const uint4* gp = (const uint4*)(aggb32 + (size_t)r0 * 32);
#pragma unroll
    for (int i = 0; i < 8; i++) {
        int idx = t + 256 * i;
        int n = r0 + (idx >> 3);
        uint4 v = {0u, 0u, 0u, 0u};
        if (n < N) v = gp[idx];
        *(uint4*)(tile + idx * 4) = v;
    }
    float wcol[64];
#pragma unroll
    for (int k = 0; k < 64; k++) wcol[k] = W[k * 64 + lane];
    __syncthreads();

    float psum = 0.f, psq = 0.f;
    for (int rr = 0; rr < 64; rr += 2) {
        int lr0 = w * 64 + rr;
        int n0 = r0 + lr0;
        if (n0 >= N) break;
        const unsigned* row0 = tile + lr0 * 32;
        const unsigned* row1 = row0 + 32;
        float o0 = 0.f, o1 = 0.f;
#pragma unroll
        for (int kp = 0; kp < 32; kp++) {
            unsigned u0 = row0[kp], u1 = row1[kp];
            o0 = fmaf(bf2f(u0 & 0xFFFFu), wcol[2 * kp], o0);
            o0 = fmaf(bf2f(u0 >> 16), wcol[2 * kp + 1], o0);
            o1 = fmaf(bf2f(u1 & 0xFFFFu), wcol[2 * kp], o1);
            o1 = fmaf(bf2f(u1 >> 16), wcol[2 * kp + 1], o1);
        }
        psum += o0;
        psq = fmaf(o0, o0, psq);
        if (n0 + 1 < N) {
            psum += o1;
            psq = fmaf(o1, o1, psq);
        }
    }
    red[w * 64 + lane] = psum;
    red[256 + w * 64 + lane] = psq;
    __syncthreads();
    if (w == 0) {
        float s = red[lane] + red[64 + lane] + red[128 + lane] + red[192 + lane];
        atomicAdd(&stats[lane], s);
    } else if (w == 1) {
        float q = red[256 + lane] + red[320 + lane] + red[384 + lane] + red[448 + lane];
        atomicAdd(&stats[64 + lane], q);
    }
}

// out = BN(agg@W)+ReLU, BN scale/shift derived in-prologue from stats (bnprep
// folded in). lane=channel; agg rows staged in LDS; store = 1 dword/lane =
// 256B contiguous per row (full lines, no amplification).
__global__ __launch_bounds__(256) void k_gemm2(const unsigned* __restrict__ aggb32,
                                               const float* __restrict__ W,
                                               const float* __restrict__ stats,
                                               const float* __restrict__ gamma,
                                               const float* __restrict__ beta,
                                               float* __restrict__ out, int N,
                                               float invN) {
    __shared__ unsigned tile[256 * 32];
    __shared__ float ssl[128];
    int t = threadIdx.x;
    int lane = t & 63;
    int w = t >> 6;
    int r0 = blockIdx.x * 256;
    const uint4* gp = (const uint4*)(aggb32 + (size_t)r0 * 32);
#pragma unroll
    for (int i = 0; i < 8; i++) {
        int idx = t + 256 * i;
        int n = r0 + (idx >> 3);
        uint4 v = {0u, 0u, 0u, 0u};
        if (n < N) v = gp[idx];
        *(uint4*)(tile + idx * 4) = v;
    }
    if (t < 64) {  // bnprep folded in (redundant per block, trivial)
        float mean = stats[t] * invN;
        float var = stats[64 + t] * invN - mean * mean;  // biased var
        float sc = gamma[t] * rsqrtf(var + BN_EPS);
        ssl[t] = sc;
        ssl[64 + t] = beta[t] - mean * sc;
    }
    float wcol[64];
#pragma unroll
    for (int k = 0; k < 64; k++) wcol[k] = W[k * 64 + lane];
    __syncthreads();
    float sc = ssl[lane], sh = ssl[64 + lane];

    for (int rr = 0; rr < 64; rr += 2) {
        int lr0 = w * 64 + rr;
        int n0 = r0 + lr0;
        if (n0 >= N) break;
        const unsigned* row0 = tile + lr0 * 32;
        const unsigned* row1 = row0 + 32;
        float o0 = 0.f, o1 = 0.f;
#pragma unroll
        for (int kp = 0; kp < 32; kp++) {
            unsigned u0 = row0[kp], u1 = row1[kp];
            o0 = fmaf(bf2f(u0 & 0xFFFFu), wcol[2 * kp], o0);
            o0 = fmaf(bf2f(u0 >> 16), wcol[2 * kp + 1], o0);
            o1 = fmaf(bf2f(u1 & 0xFFFFu), wcol[2 * kp], o1);
            o1 = fmaf(bf2f(u1 >> 16), wcol[2 * kp + 1], o1);
        }
        o0 = fmaxf(fmaf(o0, sc, sh), 0.f);
        o1 = fmaxf(fmaf(o1, sc, sh), 0.f);
        out[(size_t)n0 * 64 + lane] = o0;
        if (n0 + 1 < N) out[(size_t)(n0 + 1) * 64 + lane] = o1;
    }
}

extern "C" void kernel_launch(void* const* d_in, const int* in_sizes, int n_in,
                              void* d_out, int out_size, void* d_ws, size_t ws_size,
                              hipStream_t stream) {
    const float* x = (const float*)d_in[0];
    const int* ei = (const int*)d_in[1];
    const float* W = (const float*)d_in[2];
    // d_in[3] = bias: cancels inside BatchNorm, unused.
    const float* gamma = (const float*)d_in[4];
    const float* beta = (const float*)d_in[5];
    float* out = (float*)d_out;

    const int N = in_sizes[0] / 64;
    const int E = in_sizes[1] / 2;
    const int* src = ei;
    const int* dst = ei + E;
    const int NB = (N + 255) / 256;             // 391
    const int B = (N + NPB - 1) >> NPB_SHIFT;   // 13 coarse buckets
    const int SUBTOT = B * 64;                  // 832 sub-buckets (<=1024)
    // Slack capacity per coarse bucket: mean bucket count is E*8192/N ~= 131K,
    // sigma ~= 350. E/12 + 16384 ~= mean + 53 sigma -> overflow impossible.
    const int cap = E / 12 + 16384;

    char* ws = (char*)d_ws;
    size_t o = 0;
    float* stats = (float*)(ws + o); o += 512;       // zeroed in k_scanSub
    int* cnt2 = (int*)(ws + o); o += 4096;           // 832 ints used
    int* bcnt = (int*)(ws + o); o += 64;             // 13 coarse cursors
    size_t z0 = 512, z1 = 4096 + 64;                 // memset covers cnt2+bcnt
    int* sbase = (int*)(ws + o); o += 3584;          // SUBTOT+1 ints
    int* scur = (int*)(ws + o); o += 3584;
    int* deg = (int*)(ws + o); o += (size_t)4 * N;
    int* offs = (int*)(ws + o); o += (size_t)4 * N;
    float* dinv = (float*)(ws + o); o += (size_t)4 * N;
    unsigned short* xb = (unsigned short*)(ws + o); o += (size_t)128 * N;
    unsigned* aggb32 = (unsigned*)(ws + o); o += (size_t)128 * N;
    unsigned* binned = (unsigned*)(ws + o); o += (size_t)4 * B * cap;
    unsigned* sorted2 = (unsigned*)(ws + o); o += (size_t)4 * E;
    int* csr = (int*)binned;  // alias: binned consumed by k_sub before k_csr

    hipMemsetAsync(ws + z0, 0, z1, stream);

    int n4 = N * 16;
    int preBlocks = ((n4 + 255) / 256 > (E + 4095) / 4096) ? (n4 + 255) / 256
                                                           : (E + 4095) / 4096;
    k_pre<<<preBlocks, 256, 0, stream>>>(x, src, dst, xb, cnt2, bcnt, binned,
                                         E, n4, SUBTOT, cap);
    k_scanSub<<<1, 1024, 0, stream>>>(cnt2, sbase, scur, stats, SUBTOT, E);
    k_sub<<<B * 32, 256, 0, stream>>>(binned, sbase, scur, sorted2, cap, B);
    k_csr<<<SUBTOT, 256, 0, stream>>>(sorted2, sbase, deg, dinv, offs, csr, N);
    k_agg<<<2048, 256, 0, stream>>>(offs, deg, csr, xb, dinv, aggb32, N);
    k_gemm1<<<NB, 256, 0, stream>>>(aggb32, W, stats, N);
    k_gemm2<<<NB, 256, 0, stream>>>(aggb32, W, stats, gamma, beta, out, N,
                                    1.0f / (float)N);
}